// Round 8
// baseline (413.925 us; speedup 1.0000x reference)
//
#include <hip/hip_runtime.h>
#include <hip/hip_bf16.h>

#define B_   8
#define CH_  256
#define CQK_ 32
#define H_   128
#define W_   128

typedef __attribute__((ext_vector_type(8))) short s16x8;
typedef __attribute__((ext_vector_type(4))) float f32x4;
typedef __attribute__((ext_vector_type(4))) unsigned short u16x4;

__device__ __forceinline__ unsigned short f2b(float f) {
  __hip_bfloat16 h = __float2bfloat16(f);
  return *(unsigned short*)&h;
}
__device__ __forceinline__ float b2f(unsigned short u) {
  return __uint_as_float(((unsigned)u) << 16);
}

// ---------------- fast path ----------------
// Pipeline (R8 = R4 structure): kw_pack -> k0_xpose (xt[b][w][h][c])
//   -> k0b_xpose (xt2[b][w][c][h], staged in d_out) -> k1y (QK, E, softmax, Y=att*X' -> y)
//   -> k2g (out = gamma*(Wv.Y + bv) + x).
// R5 lesson: out layout forces block-per-(b,h) -> y intermediate is structural.
// R6 lesson: P4 reg-prefetch neutral (xt2 L2-resident already hidden).
// R7 lesson: BK=32 + launch_bounds(,4) regressed (VGPR starvation + 2x barrier drains).
// R8: k2g = R3 config (BK=64, dbuf, x-prefetch) + float4 LDS-bounce epilogue.

__global__ void kw_pack(const float* __restrict__ Wq, const float* __restrict__ Wk,
                        const float* __restrict__ Wv, unsigned short* __restrict__ wqk,
                        unsigned short* __restrict__ wv) {
  int idx = blockIdx.x * 256 + threadIdx.x;
  if (idx < 64 * 256) {
    int qc = idx >> 8, c = idx & 255;
    wqk[idx] = f2b(qc < 32 ? Wq[qc * 256 + c] : Wk[(qc - 32) * 256 + c]);
  } else {
    int i2 = idx - 64 * 256;  // < 65536
    wv[i2] = f2b(Wv[i2]);
  }
}

// K0: x[b][c][h][w] fp32 -> xt[b][w][h][c] bf16. Block per (b,h). (verified R2)
__global__ __launch_bounds__(256) void k0_xpose(const float* __restrict__ x,
                                                unsigned short* __restrict__ xt) {
  __shared__ unsigned short st[256 * 137];
  const int t = threadIdx.x;
  const int b = blockIdx.x >> 7;
  const int h = blockIdx.x & 127;
  const float* xin = x + ((size_t)b * 256 * 128 + h) * 128;
  const int w = t & 127, chalf = t >> 7;
#pragma unroll 8
  for (int it = 0; it < 128; ++it) {
    int c = it * 2 + chalf;
    st[c * 137 + w] = f2b(xin[(size_t)c * 16384 + w]);
  }
  __syncthreads();
  unsigned short* xo = xt + ((size_t)b * 128 * 128 + h) * 256;
  const int cl = t & 127, whalf = t >> 7;
#pragma unroll 8
  for (int it = 0; it < 64; ++it) {
    int wr = it * 2 + whalf;
    unsigned v = (unsigned)st[(2 * cl) * 137 + wr] |
                 ((unsigned)st[(2 * cl + 1) * 137 + wr] << 16);
    *(unsigned*)&xo[(size_t)wr * 32768 + 2 * cl] = v;
  }
}

// K0b: xt[b][w][h][c] -> xt2[b][w][c][h]. Block per (b,w): contiguous 64KB in/out.
__global__ __launch_bounds__(256, 2) void k0b_xpose(const unsigned short* __restrict__ xt,
                                                    unsigned short* __restrict__ xt2) {
  __shared__ unsigned short st[128 * 264];  // [h][c], +8 pad
  const int t = threadIdx.x;
  const size_t colbase = (size_t)blockIdx.x * 32768;
#pragma unroll
  for (int it = 0; it < 16; ++it) {
    int ch = it * 256 + t;
    int row = ch >> 5, off = (ch & 31) * 8;
    *(uint4*)&st[row * 264 + off] = *(const uint4*)&xt[colbase + ch * 8];
  }
  __syncthreads();
  // write [c][h]; thread covers (c, h-pair): banks = 8*(t&3) + c/2 -> 2-way subword only
  const int hpl = t & 3, cq = t >> 2;  // cq 0..63
#pragma unroll 8
  for (int it = 0; it < 64; ++it) {
    const int itc = it & 3, ith = it >> 2;
    const int c = itc * 64 + cq;
    const int hp = ith * 4 + hpl;
    unsigned v = (unsigned)st[(2 * hp) * 264 + c] |
                 ((unsigned)st[(2 * hp + 1) * 264 + c] << 16);
    *(unsigned*)&xt2[colbase + (size_t)c * 128 + hp * 2] = v;
  }
}

// ---- staging helper (verified R2/R4): stage one 16KB tile (128 rows x 64 bf16)
// from gsrc (row stride 256 elem) k-slice k0 into linear LDS, with inverse-XOR-swizzled
// SOURCE so that swizzled READS (byte ^ ((row&7)<<4)) return linear data (rule 21).
__device__ __forceinline__ void gld_lds16(const unsigned short* g, unsigned short* l) {
  __builtin_amdgcn_global_load_lds(
      (const __attribute__((address_space(1))) void*)g,
      (__attribute__((address_space(3))) void*)l, 16, 0, 0);
}

__device__ __forceinline__ void stage_tile(const unsigned short* __restrict__ gsrc,
                                           unsigned short* lds, int k0,
                                           int wv_id, int lane) {
#pragma unroll
  for (int i = 0; i < 4; ++i) {
    const int chunk = wv_id * 4 + i;
    const int L = chunk * 1024 + lane * 16;       // linear LDS byte this lane fills
    const int row = L >> 7;                       // 128B per row
    const int sb = L & 127;
    const int srcb = sb ^ ((row & 7) << 4);       // inverse-swizzled source slot
    gld_lds16(gsrc + row * 256 + k0 + (srcb >> 1), lds + chunk * 512);
  }
}

// K1y (R4-verified form): per (b,w): QK GEMM (B staged via global_load_lds dbuf),
// E GEMM, in-register softmax, Y = att * X' (B from xt2 col), y[b][h][w][c] bf16 out.
struct SmemY {
  unsigned short qt[128 * 40];     // [h][qc]  10240 B
  unsigned short kt[128 * 40];     //          10240 B
  union {
    unsigned short att[128 * 136]; // [i][j] bf16; reused as ybuf[i][c-half] 34816 B
    unsigned short xstage[2][128 * 64]; // P1 staging dbuf (dead before att written)
  } u;
};                               // total 55296 B -> 2 blocks/CU

__global__ __launch_bounds__(256, 2)
void k1y(const unsigned short* __restrict__ xt, const unsigned short* __restrict__ xt2,
         const unsigned short* __restrict__ wqk, const float* __restrict__ bq,
         const float* __restrict__ bk, unsigned short* __restrict__ y) {
  __shared__ SmemY sm;
  const int t = threadIdx.x;
  const int wvid = t >> 6;
  const int lane = t & 63;
  const int l15 = lane & 15;
  const int quad = lane >> 4;
  const int b = blockIdx.x >> 7;
  const int w = blockIdx.x & 127;
  const size_t colbase = ((size_t)b * 128 + w) * 32768;

  // ---- P1: QK GEMM. M=qc(16/wave), N=h(128), K=c(256). B staged via dbuf gld_lds.
  {
    const int qc0 = wvid * 16;
    f32x4 acc[8];
#pragma unroll
    for (int nt = 0; nt < 8; ++nt) acc[nt] = {0.f, 0.f, 0.f, 0.f};
    const unsigned short* arow = wqk + (qc0 + l15) * 256 + quad * 8;
    const unsigned short* gcol = xt + colbase;  // 128 h-rows, stride 256 elem
    stage_tile(gcol, sm.u.xstage[0], 0, wvid, lane);
    __syncthreads();  // drains vmcnt
#pragma unroll
    for (int kc = 0; kc < 4; ++kc) {
      const int cur = kc & 1;
      if (kc < 3) stage_tile(gcol, sm.u.xstage[cur ^ 1], (kc + 1) * 64, wvid, lane);
#pragma unroll
      for (int kk2 = 0; kk2 < 2; ++kk2) {
        s16x8 a = *(const s16x8*)(arow + (kc * 2 + kk2) * 32);
#pragma unroll
        for (int nt = 0; nt < 8; ++nt) {
          const int row = nt * 16 + l15;
          const int col = (kk2 * 64 + quad * 16) ^ ((row & 7) << 4);
          s16x8 bb = *(const s16x8*)((const char*)sm.u.xstage[cur] + row * 128 + col);
          acc[nt] = __builtin_amdgcn_mfma_f32_16x16x32_bf16(a, bb, acc[nt], 0, 0, 0);
        }
      }
      __syncthreads();  // staged buf ready; all reads of cur done before overwrite
    }
    const float* bp = (wvid < 2) ? bq : bk;
    const int qcl = qc0 & 16;
    float bias[4];
#pragma unroll
    for (int r = 0; r < 4; ++r) bias[r] = bp[qcl + quad * 4 + r];
    unsigned short* dst = (wvid < 2) ? sm.qt : sm.kt;
#pragma unroll
    for (int nt = 0; nt < 8; ++nt) {
      int h = nt * 16 + l15;
      u16x4 pk;
#pragma unroll
      for (int r = 0; r < 4; ++r) pk[r] = f2b(acc[nt][r] + bias[r]);
      *(u16x4*)&dst[h * 40 + qcl + quad * 4] = pk;
    }
  }
  __syncthreads();

  // ---- P2: E GEMM (rows i0..i0+31 per wave, all j). D stays in registers.
  {
    const int i0 = wvid * 32;
    s16x8 aQ[2];
#pragma unroll
    for (int mt = 0; mt < 2; ++mt)
      aQ[mt] = *(const s16x8*)&sm.qt[(i0 + mt * 16 + l15) * 40 + quad * 8];
    f32x4 eacc[2][8];
#pragma unroll
    for (int mt = 0; mt < 2; ++mt)
#pragma unroll
      for (int nt = 0; nt < 8; ++nt) eacc[mt][nt] = {0.f, 0.f, 0.f, 0.f};
#pragma unroll
    for (int nt = 0; nt < 8; ++nt) {
      s16x8 bK = *(const s16x8*)&sm.kt[(nt * 16 + l15) * 40 + quad * 8];
      eacc[0][nt] = __builtin_amdgcn_mfma_f32_16x16x32_bf16(aQ[0], bK, eacc[0][nt], 0, 0, 0);
      eacc[1][nt] = __builtin_amdgcn_mfma_f32_16x16x32_bf16(aQ[1], bK, eacc[1][nt], 0, 0, 0);
    }
    // ---- P3: in-register softmax. Row i = i0+mt*16+quad*4+r lives in the 16 lanes
    // of one quad group (cols j = nt*16+l15). Diagonal mask, then 16-lane shfl reduce.
#pragma unroll
    for (int mt = 0; mt < 2; ++mt)
#pragma unroll
      for (int nt = 0; nt < 8; ++nt) {
        const int j = nt * 16 + l15;
#pragma unroll
        for (int r = 0; r < 4; ++r)
          if (j == i0 + mt * 16 + quad * 4 + r) eacc[mt][nt][r] = -__builtin_inff();
      }
#pragma unroll
    for (int mt = 0; mt < 2; ++mt)
#pragma unroll
      for (int r = 0; r < 4; ++r) {
        float mx = -__builtin_inff();
#pragma unroll
        for (int nt = 0; nt < 8; ++nt) mx = fmaxf(mx, eacc[mt][nt][r]);
        mx = fmaxf(mx, __shfl_xor(mx, 1));
        mx = fmaxf(mx, __shfl_xor(mx, 2));
        mx = fmaxf(mx, __shfl_xor(mx, 4));
        mx = fmaxf(mx, __shfl_xor(mx, 8));
        float s = 0.f;
#pragma unroll
        for (int nt = 0; nt < 8; ++nt) {
          float p = __expf(eacc[mt][nt][r] - mx);
          eacc[mt][nt][r] = p;
          s += p;
        }
        s += __shfl_xor(s, 1);
        s += __shfl_xor(s, 2);
        s += __shfl_xor(s, 4);
        s += __shfl_xor(s, 8);
        const float inv = 1.0f / s;
        const int i = i0 + mt * 16 + quad * 4 + r;
#pragma unroll
        for (int nt = 0; nt < 8; ++nt)
          sm.u.att[i * 136 + nt * 16 + l15] = f2b(eacc[mt][nt][r] * inv);
      }
  }
  __syncthreads();

  // ---- P4: Y GEMM. M=i(128), N=c(64/wave), K=j(128). A=att (LDS), B=xt2 col (global).
  f32x4 yacc[8][4];
#pragma unroll
  for (int mt = 0; mt < 8; ++mt)
#pragma unroll
    for (int nt = 0; nt < 4; ++nt) yacc[mt][nt] = {0.f, 0.f, 0.f, 0.f};
  {
    const int c0 = wvid * 64;
#pragma unroll
    for (int kj = 0; kj < 4; ++kj) {
      s16x8 aP[8];
#pragma unroll
      for (int mt = 0; mt < 8; ++mt)
        aP[mt] = *(const s16x8*)&sm.u.att[(mt * 16 + l15) * 136 + kj * 32 + quad * 8];
#pragma unroll
      for (int nt = 0; nt < 4; ++nt) {
        s16x8 bX = *(const s16x8*)&xt2[colbase + (size_t)(c0 + nt * 16 + l15) * 128 +
                                        kj * 32 + quad * 8];
#pragma unroll
        for (int mt = 0; mt < 8; ++mt)
          yacc[mt][nt] = __builtin_amdgcn_mfma_f32_16x16x32_bf16(aP[mt], bX, yacc[mt][nt], 0, 0, 0);
      }
    }
  }
  // ---- P5: store y in two c-halves via ybuf (aliases att; all A-reads done).
#pragma unroll 1
  for (int h2 = 0; h2 < 2; ++h2) {
    __syncthreads();
    if ((wvid >> 1) == h2) {
      const int clb = (wvid & 1) * 64;
#pragma unroll
      for (int mt = 0; mt < 8; ++mt)
#pragma unroll
        for (int nt = 0; nt < 4; ++nt) {
          const int cl = clb + nt * 16 + l15;
#pragma unroll
          for (int r = 0; r < 4; ++r)
            sm.u.att[(mt * 16 + quad * 4 + r) * 136 + cl] = f2b(yacc[mt][nt][r]);
        }
    }
    __syncthreads();
#pragma unroll
    for (int it = 0; it < 8; ++it) {
      int g = it * 256 + t;
      int i = g >> 4, cc = (g & 15) * 8;
      *(uint4*)&y[((size_t)(b * 128 + i) * 128 + w) * 256 + h2 * 128 + cc] =
          *(const uint4*)&sm.u.att[i * 136 + cc];
    }
  }
}

// ---------------- K2g (R8): BK=64 dbuf GEMM + float4 LDS-bounce epilogue ----------------
// out[b][co][h][w] = gamma*(Wv.Y + bv) + x.  Per block: 128co x 128w tile of one (b,h).
// Grid 2048. XCD pair-swizzle: bh = (bid>>4)*8 + (bid&7), mhalf = (bid>>3)&1.
// Main loop = R3-verified (BK=64, 4 kt steps, XOR-swizzle byte^((row&7)<<4), rule 21).
// R8: epilogue was 64+64 scalar 4B ops/thread (64B runs) -- the kernel's entire HBM
// traffic at 1/4 width. Now: acc -> f32 LDS bounce [64co][132] (aliases dead staging
// bufs), re-read in row-streaming map (thread=(c4=t&31, rbase=t>>5); instr i covers
// rows 8i..8i+7 full-width) -> float4 stores, 1KB/wave-instr. x-prefetch in the same
// float4 mapping, spread 4-per-kt through the main loop (compile-time indices).

struct SmemG {
  union {
    struct {
      unsigned short A[2][128 * 64];  // [buf][row=co][c'] swizzled, 16KB each
      unsigned short B[2][128 * 64];  // [buf][row=w][c']
    } s;                              // 64KB
    float ep[64 * 132];               // epilogue bounce (33792B, 16B-aligned rows)
  } u;
};                                    // 64KB -> 2 blocks/CU

__global__ __launch_bounds__(256, 2)
void k2g(const unsigned short* __restrict__ y, const unsigned short* __restrict__ wv,
         const float* __restrict__ bv, const float* __restrict__ gamma,
         const float* __restrict__ x, float* __restrict__ out) {
  __shared__ SmemG sm;
  const int t = threadIdx.x;
  const int wv_id = t >> 6;
  const int lane = t & 63;
  const int l15 = lane & 15;
  const int quad = lane >> 4;
  // XCD pair-swizzle (bijective): paired co-halves -> same XCD (bid%8 preserved).
  const int mhalf = (blockIdx.x >> 3) & 1;
  const int bh = ((blockIdx.x >> 4) << 3) | (blockIdx.x & 7);
  const int b = bh >> 7, h = bh & 127;
  const unsigned short* gA = wv + mhalf * 128 * 256;      // 128 co rows
  const unsigned short* gB = y + (size_t)bh * 128 * 256;  // 128 w rows
  const int wr = wv_id >> 1;   // co 64-half within tile
  const int wc = wv_id & 1;    // w 64-half within tile
  // epilogue mapping: c4 = float4 w-column, rbase = co row base
  const int c4 = t & 31;
  const int rbase = t >> 5;
  const float4* x4 = (const float4*)x;
  float4* out4 = (float4*)out;

  f32x4 acc[4][4];
#pragma unroll
  for (int mt = 0; mt < 4; ++mt)
#pragma unroll
    for (int nt = 0; nt < 4; ++nt) acc[mt][nt] = {0.f, 0.f, 0.f, 0.f};
  float4 xpf[2][8];  // [hf][i] epilogue x operand, float4, prefetched in kt loop

  // prologue: stage K-chunk 0 into buf 0
  stage_tile(gA, sm.u.s.A[0], 0, wv_id, lane);
  stage_tile(gB, sm.u.s.B[0], 0, wv_id, lane);
  __syncthreads();  // drains vmcnt

#pragma unroll
  for (int kt = 0; kt < 4; ++kt) {
    const int cur = kt & 1;
    if (kt < 3) {  // issue next-chunk loads (async, vmcnt-tracked)
      stage_tile(gA, sm.u.s.A[cur ^ 1], (kt + 1) * 64, wv_id, lane);
      stage_tile(gB, sm.u.s.B[cur ^ 1], (kt + 1) * 64, wv_id, lane);
    }
    // x prefetch quarter: 4 float4 per kt (indices compile-time via unroll).
    // In flight during this kt's MFMAs; drained by this kt's barrier.
#pragma unroll
    for (int j = 0; j < 4; ++j) {
      const int idx = kt * 4 + j;
      const int hf = idx >> 3, i = idx & 7;
      const int co = mhalf * 128 + hf * 64 + rbase + 8 * i;
      xpf[hf][i] = x4[((size_t)(b * 256 + co) * 128 + h) * 32 + c4];
    }
    // compute current buffer: 2 k-substeps of 32, 16 MFMA each
#pragma unroll
    for (int ks = 0; ks < 2; ++ks) {
      s16x8 a[4], bb[4];
#pragma unroll
      for (int mt = 0; mt < 4; ++mt) {
        const int row = wr * 64 + mt * 16 + l15;
        const int col = (ks * 64 + quad * 16) ^ ((row & 7) << 4);
        a[mt] = *(const s16x8*)((const char*)&sm.u.s.A[cur][0] + row * 128 + col);
      }
#pragma unroll
      for (int nt = 0; nt < 4; ++nt) {
        const int row = wc * 64 + nt * 16 + l15;
        const int col = (ks * 64 + quad * 16) ^ ((row & 7) << 4);
        bb[nt] = *(const s16x8*)((const char*)&sm.u.s.B[cur][0] + row * 128 + col);
      }
#pragma unroll
      for (int nt = 0; nt < 4; ++nt)
#pragma unroll
        for (int mt = 0; mt < 4; ++mt)
          acc[mt][nt] = __builtin_amdgcn_mfma_f32_16x16x32_bf16(a[mt], bb[nt], acc[mt][nt], 0, 0, 0);
    }
    __syncthreads();  // staged buf ready; all reads of cur done before overwrite
  }
  // (final barrier above also means staging bufs are dead -> ep reuse safe)

  // epilogue: per co-half: acc -> LDS bounce -> float4 read -> out = g*(v+bv)+x.
  const float g = gamma[0];
#pragma unroll 1
  for (int hf = 0; hf < 2; ++hf) {
    if (wr == hf) {
      // write acc: rows co_local = mt*16+quad*4+r, cols w = wc*64+nt*16+l15.
      // banks: 132*4 = 528 ≡ 16 (mod 32) per quad -> 2-way, free.
#pragma unroll
      for (int mt = 0; mt < 4; ++mt)
#pragma unroll
        for (int nt = 0; nt < 4; ++nt)
#pragma unroll
          for (int r = 0; r < 4; ++r)
            sm.u.ep[(mt * 16 + quad * 4 + r) * 132 + wc * 64 + nt * 16 + l15] =
                acc[mt][nt][r];
    }
    __syncthreads();
#pragma unroll
    for (int i = 0; i < 8; ++i) {
      const int co_local = rbase + 8 * i;
      const int co = mhalf * 128 + hf * 64 + co_local;
      const float4 v = *(const float4*)&sm.u.ep[co_local * 132 + c4 * 4];
      const float bvv = bv[co];
      const float4 xr = xpf[hf][i];
      float4 o;
      o.x = g * (v.x + bvv) + xr.x;
      o.y = g * (v.y + bvv) + xr.y;
      o.z = g * (v.z + bvv) + xr.z;
      o.w = g * (v.w + bvv) + xr.w;
      out4[((size_t)(b * 256 + co) * 128 + h) * 32 + c4] = o;
    }
    if (hf == 0) __syncthreads();  // reads done before half-1 overwrites ep
  }
}

// ---------------- fallback path (round-1 verified, used only if ws too small) ----------------

struct SmemK1 {
  __hip_bfloat16 x[CH_][H_];
  float att[H_][130];
  union {
    struct { __hip_bfloat16 q[CQK_][H_]; __hip_bfloat16 k[CQK_][H_]; } qk;
    float vchunk[32][130];
  } s;
};

__device__ __forceinline__ void load_bf16x16(const __hip_bfloat16* p, float* f) {
  const uint4* p4 = (const uint4*)p;
  uint4 a = p4[0], b = p4[1];
  unsigned uu[8] = {a.x, a.y, a.z, a.w, b.x, b.y, b.z, b.w};
#pragma unroll
  for (int m = 0; m < 8; ++m) {
    f[2 * m] = __uint_as_float(uu[m] << 16);
    f[2 * m + 1] = __uint_as_float(uu[m] & 0xffff0000u);
  }
}

__global__ __launch_bounds__(256, 1)
void k1_attn(const float* __restrict__ x, const float* __restrict__ Wq,
             const float* __restrict__ bq, const float* __restrict__ Wk,
             const float* __restrict__ bk, const float* __restrict__ Wv,
             const float* __restrict__ bv, float* __restrict__ o_t) {
  __shared__ SmemK1 sm;
  const int t = threadIdx.x;
  const int b = blockIdx.x >> 7;
  const int w = blockIdx.x & 127;
  {
    const float* xb = x + (size_t)b * CH_ * H_ * W_ + w;
    const int h = t & 127;
    const int c0 = (t >> 7) * 128;
#pragma unroll 8
    for (int r = 0; r < 128; ++r) {
      const int c = c0 + r;
      sm.x[c][h] = __float2bfloat16(xb[(size_t)(c * H_ + h) * W_]);
    }
  }
  __syncthreads();
  {
    const int qc = t >> 3;
    const int i0 = (t & 7) << 4;
    float qa[16], ka[16];
    const float bqv = bq[qc], bkv = bk[qc];
#pragma unroll
    for (int u = 0; u < 16; ++u) { qa[u] = bqv; ka[u] = bkv; }
    const float* wqr = Wq + qc * CH_;
    const float* wkr = Wk + qc * CH_;
    for (int c = 0; c < CH_; c += 4) {
      const float4 wq4 = *(const float4*)(wqr + c);
      const float4 wk4 = *(const float4*)(wkr + c);
      const float wqs[4] = {wq4.x, wq4.y, wq4.z, wq4.w};
      const float wks[4] = {wk4.x, wk4.y, wk4.z, wk4.w};
#pragma unroll
      for (int cc = 0; cc < 4; ++cc) {
        float xf[16];
        load_bf16x16(&sm.x[c + cc][i0], xf);
#pragma unroll
        for (int u = 0; u < 16; ++u) {
          qa[u] += wqs[cc] * xf[u];
          ka[u] += wks[cc] * xf[u];
        }
      }
    }
#pragma unroll
    for (int u = 0; u < 16; ++u) {
      sm.s.qk.q[qc][i0 + u] = __float2bfloat16(qa[u]);
      sm.s.qk.k[qc][i0 + u] = __float2bfloat16(ka[u]);
    }
  }
  __syncthreads();
  {
    const int i = t >> 1;
    const int j0 = (t & 1) << 6;
    float qreg[32];
#pragma unroll
    for (int qc = 0; qc < 32; ++qc) qreg[qc] = __bfloat162float(sm.s.qk.q[qc][i]);
    float e[64];
#pragma unroll
    for (int u = 0; u < 64; ++u) e[u] = 0.0f;
    for (int qc = 0; qc < 32; ++qc) {
#pragma unroll
      for (int jc = 0; jc < 4; ++jc) {
        float kf[16];
        load_bf16x16(&sm.s.qk.k[qc][j0 + jc * 16], kf);
#pragma unroll
        for (int u = 0; u < 16; ++u) e[jc * 16 + u] += qreg[qc] * kf[u];
      }
    }
    if (i >= j0 && i < j0 + 64) e[i - j0] = -__builtin_inff();
    float m = -__builtin_inff();
#pragma unroll
    for (int u = 0; u < 64; ++u) m = fmaxf(m, e[u]);
    m = fmaxf(m, __shfl_xor(m, 1));
    float ssum = 0.0f;
#pragma unroll
    for (int u = 0; u < 64; ++u) { e[u] = __expf(e[u] - m); ssum += e[u]; }
    ssum += __shfl_xor(ssum, 1);
    const float inv = 1.0f / ssum;
#pragma unroll
    for (int u = 0; u < 64; u += 2)
      *(float2*)&sm.att[i][j0 + u] = make_float2(e[u] * inv, e[u + 1] * inv);
  }
  __syncthreads();
  const int vcc = t >> 3;
  const int vj0 = (t & 7) << 4;
  const int ai0 = (t >> 3) << 2;
  const int acc0 = (t & 7) << 2;
  for (int ch = 0; ch < 8; ++ch) {
    {
      const int cg = ch * 32 + vcc;
      float acc[16];
      const float bvv = bv[cg];
#pragma unroll
      for (int u = 0; u < 16; ++u) acc[u] = bvv;
      const float* wvr = Wv + (size_t)cg * CH_;
      for (int c = 0; c < CH_; c += 4) {
        const float4 w4 = *(const float4*)(wvr + c);
        const float ws4[4] = {w4.x, w4.y, w4.z, w4.w};
#pragma unroll
        for (int cc = 0; cc < 4; ++cc) {
          float xf[16];
          load_bf16x16(&sm.x[c + cc][vj0], xf);
#pragma unroll
          for (int u = 0; u < 16; ++u) acc[u] += ws4[cc] * xf[u];
        }
      }
#pragma unroll
      for (int m2 = 0; m2 < 8; ++m2)
        *(float2*)&sm.s.vchunk[vcc][vj0 + 2 * m2] = make_float2(acc[2 * m2], acc[2 * m2 + 1]);
    }
    __syncthreads();
    {
      float oacc[4][4];
#pragma unroll
      for (int s2 = 0; s2 < 4; ++s2)
#pragma unroll
        for (int u = 0; u < 4; ++u) oacc[s2][u] = 0.0f;
#pragma unroll 4
      for (int j = 0; j < H_; j += 2) {
        float2 av[4], vv[4];
#pragma unroll
        for (int u = 0; u < 4; ++u) av[u] = *(const float2*)&sm.att[ai0 + u][j];
#pragma unroll
        for (int s2 = 0; s2 < 4; ++s2) vv[s2] = *(const float2*)&sm.s.vchunk[acc0 + s2][j];
#pragma unroll
        for (int s2 = 0; s2 < 4; ++s2)
#pragma unroll
          for (int u = 0; u < 4; ++u)
            oacc[s2][u] += vv[s2].x * av[u].x + vv[s2].y * av[u].y;
      }
#pragma unroll
      for (int s2 = 0; s2 < 4; ++s2) {
        const int cg = ch * 32 + acc0 + s2;
        float4 st;
        st.x = oacc[s2][0]; st.y = oacc[s2][1]; st.z = oacc[s2][2]; st.w = oacc[s2][3];
        *(float4*)&o_t[(((size_t)b * CH_ + cg) * W_ + w) * H_ + ai0] = st;
      }
    }
    __syncthreads();
  }
}

__global__ __launch_bounds__(256)
void k2_epi(const float* __restrict__ o_t, const float* __restrict__ x,
            const float* __restrict__ gamma, float* __restrict__ out) {
  const int pr = blockIdx.x % 10;
  const int plane = blockIdx.x / 10;
  const int rT[10] = {0, 0, 0, 0, 1, 1, 1, 2, 2, 3};
  const int sT[10] = {0, 1, 2, 3, 1, 2, 3, 2, 3, 3};
  const int r = rT[pr], s = sT[pr];
  __shared__ float t1[32][33];
  __shared__ float t2[32][33];
  const int t = threadIdx.x;
  const size_t pbase = (size_t)plane * (H_ * W_);
  const float* ob = o_t + pbase;
#pragma unroll
  for (int ii = 0; ii < 4; ++ii) {
    const int idx = ii * 256 + t;
    const int ww = idx >> 5, hh = idx & 31;
    t1[ww][hh] = ob[(s * 32 + ww) * H_ + (r * 32 + hh)];
    if (r != s) t2[ww][hh] = ob[(r * 32 + ww) * H_ + (s * 32 + hh)];
  }
  __syncthreads();
  const float g = gamma[0];
#pragma unroll
  for (int ii = 0; ii < 4; ++ii) {
    const int idx = ii * 256 + t;
    const int hh = idx >> 5, ww = idx & 31;
    const size_t o1 = pbase + (size_t)(r * 32 + hh) * W_ + (s * 32 + ww);
    out[o1] = g * t1[ww][hh] + x[o1];
    if (r != s) {
      const size_t o2 = pbase + (size_t)(s * 32 + hh) * W_ + (r * 32 + ww);
      out[o2] = g * t2[ww][hh] + x[o2];
    }
  }
}

// ---------------- launch ----------------

extern "C" void kernel_launch(void* const* d_in, const int* in_sizes, int n_in,
                              void* d_out, int out_size, void* d_ws, size_t ws_size,
                              hipStream_t stream) {
  const float* x     = (const float*)d_in[0];
  const float* Wq    = (const float*)d_in[1];
  const float* bq    = (const float*)d_in[2];
  const float* Wk    = (const float*)d_in[3];
  const float* bk    = (const float*)d_in[4];
  const float* Wv    = (const float*)d_in[5];
  const float* bv    = (const float*)d_in[6];
  const float* gamma = (const float*)d_in[7];
  float* out = (float*)d_out;

  const size_t XT   = (size_t)B_ * W_ * H_ * CH_ * 2;  // 64 MiB bf16
  const size_t YT   = XT;                              // 64 MiB bf16
  const size_t WQKB = 64 * 256 * 2;
  const size_t WVB  = 256 * 256 * 2;
  const size_t FAST_WS = XT + YT + WQKB + WVB;

  if (ws_size >= FAST_WS) {
    unsigned short* xt  = (unsigned short*)d_ws;
    unsigned short* yb  = (unsigned short*)((char*)d_ws + XT);
    unsigned short* wqk = (unsigned short*)((char*)d_ws + XT + YT);
    unsigned short* wvb = (unsigned short*)((char*)d_ws + XT + YT + WQKB);
    // xt2 lives in d_out (64 of 128 MiB): dead before k2g overwrites out.
    unsigned short* xt2 = (unsigned short*)d_out;
    hipLaunchKernelGGL(kw_pack, dim3(320), dim3(256), 0, stream, Wq, Wk, Wv, wqk, wvb);
    hipLaunchKernelGGL(k0_xpose, dim3(B_ * H_), dim3(256), 0, stream, x, xt);
    hipLaunchKernelGGL(k0b_xpose, dim3(B_ * W_), dim3(256), 0, stream, xt, xt2);
    hipLaunchKernelGGL(k1y, dim3(B_ * W_), dim3(256), 0, stream,
                       xt, xt2, wqk, bq, bk, yb);
    hipLaunchKernelGGL(k2g, dim3(B_ * H_ * 2), dim3(256), 0, stream,
                       yb, wvb, bv, gamma, x, out);
  } else {
    const size_t OT_F = (size_t)B_ * CH_ * H_ * W_ * sizeof(float);
    float* o_t = (ws_size >= OT_F) ? (float*)d_ws : out;
    hipLaunchKernelGGL(k1_attn, dim3(B_ * W_), dim3(256), 0, stream,
                       x, Wq, bq, Wk, bk, Wv, bv, o_t);
    hipLaunchKernelGGL(k2_epi, dim3((B_ * CH_) * 10), dim3(256), 0, stream,
                       o_t, x, gamma, out);
  }
}

// Round 9
// 373.668 us; speedup vs baseline: 1.1077x; 1.1077x over previous
//
#include <hip/hip_runtime.h>
#include <hip/hip_bf16.h>

#define B_   8
#define CH_  256
#define CQK_ 32
#define H_   128
#define W_   128

typedef __attribute__((ext_vector_type(8))) short s16x8;
typedef __attribute__((ext_vector_type(4))) float f32x4;
typedef __attribute__((ext_vector_type(4))) unsigned short u16x4;

__device__ __forceinline__ unsigned short f2b(float f) {
  __hip_bfloat16 h = __float2bfloat16(f);
  return *(unsigned short*)&h;
}
__device__ __forceinline__ float b2f(unsigned short u) {
  return __uint_as_float(((unsigned)u) << 16);
}

// ---------------- fast path ----------------
// Pipeline (R9 = R6 restore, session best 372.9us): kw_pack -> k0_xpose (xt[b][w][h][c])
//   -> k0b_xpose (xt2[b][w][c][h], staged in d_out) -> k1y (QK, E, softmax, Y=att*X' -> y)
//   -> k2g (out = gamma*(Wv.Y + bv) + x).
// R5 lesson: out layout forces block-per-(b,h) -> y intermediate is structural.
// R6 lesson: P4 reg-prefetch neutral (xt2 L2-resident already hidden).
// R7 lesson: BK=32 + launch_bounds(,4) regressed (VGPR starvation + 2x barrier drains).
// R8 lesson: LDS-bounce float4 epilogue regressed (bank conflicts + broke L2 write-merge;
//   scalar epilogue stores already merge to exactly out-size HBM writes).

__global__ void kw_pack(const float* __restrict__ Wq, const float* __restrict__ Wk,
                        const float* __restrict__ Wv, unsigned short* __restrict__ wqk,
                        unsigned short* __restrict__ wv) {
  int idx = blockIdx.x * 256 + threadIdx.x;
  if (idx < 64 * 256) {
    int qc = idx >> 8, c = idx & 255;
    wqk[idx] = f2b(qc < 32 ? Wq[qc * 256 + c] : Wk[(qc - 32) * 256 + c]);
  } else {
    int i2 = idx - 64 * 256;  // < 65536
    wv[i2] = f2b(Wv[i2]);
  }
}

// K0: x[b][c][h][w] fp32 -> xt[b][w][h][c] bf16. Block per (b,h). (verified R2)
__global__ __launch_bounds__(256) void k0_xpose(const float* __restrict__ x,
                                                unsigned short* __restrict__ xt) {
  __shared__ unsigned short st[256 * 137];
  const int t = threadIdx.x;
  const int b = blockIdx.x >> 7;
  const int h = blockIdx.x & 127;
  const float* xin = x + ((size_t)b * 256 * 128 + h) * 128;
  const int w = t & 127, chalf = t >> 7;
#pragma unroll 8
  for (int it = 0; it < 128; ++it) {
    int c = it * 2 + chalf;
    st[c * 137 + w] = f2b(xin[(size_t)c * 16384 + w]);
  }
  __syncthreads();
  unsigned short* xo = xt + ((size_t)b * 128 * 128 + h) * 256;
  const int cl = t & 127, whalf = t >> 7;
#pragma unroll 8
  for (int it = 0; it < 64; ++it) {
    int wr = it * 2 + whalf;
    unsigned v = (unsigned)st[(2 * cl) * 137 + wr] |
                 ((unsigned)st[(2 * cl + 1) * 137 + wr] << 16);
    *(unsigned*)&xo[(size_t)wr * 32768 + 2 * cl] = v;
  }
}

// K0b: xt[b][w][h][c] -> xt2[b][w][c][h]. Block per (b,w): contiguous 64KB in/out.
__global__ __launch_bounds__(256, 2) void k0b_xpose(const unsigned short* __restrict__ xt,
                                                    unsigned short* __restrict__ xt2) {
  __shared__ unsigned short st[128 * 264];  // [h][c], +8 pad
  const int t = threadIdx.x;
  const size_t colbase = (size_t)blockIdx.x * 32768;
#pragma unroll
  for (int it = 0; it < 16; ++it) {
    int ch = it * 256 + t;
    int row = ch >> 5, off = (ch & 31) * 8;
    *(uint4*)&st[row * 264 + off] = *(const uint4*)&xt[colbase + ch * 8];
  }
  __syncthreads();
  // write [c][h]; thread covers (c, h-pair): banks = 8*(t&3) + c/2 -> 2-way subword only
  const int hpl = t & 3, cq = t >> 2;  // cq 0..63
#pragma unroll 8
  for (int it = 0; it < 64; ++it) {
    const int itc = it & 3, ith = it >> 2;
    const int c = itc * 64 + cq;
    const int hp = ith * 4 + hpl;
    unsigned v = (unsigned)st[(2 * hp) * 264 + c] |
                 ((unsigned)st[(2 * hp + 1) * 264 + c] << 16);
    *(unsigned*)&xt2[colbase + (size_t)c * 128 + hp * 2] = v;
  }
}

// ---- shared staging helper (verified R2/R4): stage one 16KB tile
// (128 rows x 64 bf16) from gsrc (row stride 256 elem) k-slice k0 into linear LDS,
// with inverse-XOR-swizzled SOURCE so that swizzled READS (byte ^ ((row&7)<<4))
// return linear data (rule 21 pairing).
__device__ __forceinline__ void gld_lds16(const unsigned short* g, unsigned short* l) {
  __builtin_amdgcn_global_load_lds(
      (const __attribute__((address_space(1))) void*)g,
      (__attribute__((address_space(3))) void*)l, 16, 0, 0);
}

__device__ __forceinline__ void stage_tile(const unsigned short* __restrict__ gsrc,
                                           unsigned short* lds, int k0,
                                           int wv_id, int lane) {
#pragma unroll
  for (int i = 0; i < 4; ++i) {
    const int chunk = wv_id * 4 + i;
    const int L = chunk * 1024 + lane * 16;       // linear LDS byte this lane fills
    const int row = L >> 7;                       // 128B per row
    const int sb = L & 127;
    const int srcb = sb ^ ((row & 7) << 4);       // inverse-swizzled source slot
    gld_lds16(gsrc + row * 256 + k0 + (srcb >> 1), lds + chunk * 512);
  }
}

// K1y: per (b,w): QK GEMM (B staged via global_load_lds dbuf, R4), E GEMM,
// in-register softmax, Y = att * X' (B reg-prefetched from xt2, R6), y[b][h][w][c] out.
struct SmemY {
  unsigned short qt[128 * 40];     // [h][qc]  10240 B
  unsigned short kt[128 * 40];     //          10240 B
  union {
    unsigned short att[128 * 136]; // [i][j] bf16; reused as ybuf[i][c-half] 34816 B
    unsigned short xstage[2][128 * 64]; // P1 staging dbuf (dead before att written)
  } u;
};                               // total 55296 B -> 2 blocks/CU

__global__ __launch_bounds__(256, 2)
void k1y(const unsigned short* __restrict__ xt, const unsigned short* __restrict__ xt2,
         const unsigned short* __restrict__ wqk, const float* __restrict__ bq,
         const float* __restrict__ bk, unsigned short* __restrict__ y) {
  __shared__ SmemY sm;
  const int t = threadIdx.x;
  const int wvid = t >> 6;
  const int lane = t & 63;
  const int l15 = lane & 15;
  const int quad = lane >> 4;
  const int b = blockIdx.x >> 7;
  const int w = blockIdx.x & 127;
  const size_t colbase = ((size_t)b * 128 + w) * 32768;

  // ---- P1: QK GEMM. M=qc(16/wave), N=h(128), K=c(256). B staged via dbuf gld_lds.
  {
    const int qc0 = wvid * 16;
    f32x4 acc[8];
#pragma unroll
    for (int nt = 0; nt < 8; ++nt) acc[nt] = {0.f, 0.f, 0.f, 0.f};
    const unsigned short* arow = wqk + (qc0 + l15) * 256 + quad * 8;
    const unsigned short* gcol = xt + colbase;  // 128 h-rows, stride 256 elem
    stage_tile(gcol, sm.u.xstage[0], 0, wvid, lane);
    __syncthreads();  // drains vmcnt
#pragma unroll
    for (int kc = 0; kc < 4; ++kc) {
      const int cur = kc & 1;
      if (kc < 3) stage_tile(gcol, sm.u.xstage[cur ^ 1], (kc + 1) * 64, wvid, lane);
#pragma unroll
      for (int kk2 = 0; kk2 < 2; ++kk2) {
        s16x8 a = *(const s16x8*)(arow + (kc * 2 + kk2) * 32);
#pragma unroll
        for (int nt = 0; nt < 8; ++nt) {
          const int row = nt * 16 + l15;
          const int col = (kk2 * 64 + quad * 16) ^ ((row & 7) << 4);
          s16x8 bb = *(const s16x8*)((const char*)sm.u.xstage[cur] + row * 128 + col);
          acc[nt] = __builtin_amdgcn_mfma_f32_16x16x32_bf16(a, bb, acc[nt], 0, 0, 0);
        }
      }
      __syncthreads();  // staged buf ready; all reads of cur done before overwrite
    }
    const float* bp = (wvid < 2) ? bq : bk;
    const int qcl = qc0 & 16;
    float bias[4];
#pragma unroll
    for (int r = 0; r < 4; ++r) bias[r] = bp[qcl + quad * 4 + r];
    unsigned short* dst = (wvid < 2) ? sm.qt : sm.kt;
#pragma unroll
    for (int nt = 0; nt < 8; ++nt) {
      int h = nt * 16 + l15;
      u16x4 pk;
#pragma unroll
      for (int r = 0; r < 4; ++r) pk[r] = f2b(acc[nt][r] + bias[r]);
      *(u16x4*)&dst[h * 40 + qcl + quad * 4] = pk;
    }
  }
  __syncthreads();

  // ---- R6 (T14 issue-early/use-late): issue ALL P4 B-frags (xt2) now; consumed in P4.
  // Latency (~900cy HBM) hides under P2+P3. 64 VGPRs; occupancy LDS-bound -> free.
  // sched_barrier(0) pins the loads here so the compiler can't sink them to first use.
  s16x8 bXpf[4][4];
  {
    const int c0 = wvid * 64;
#pragma unroll
    for (int kj = 0; kj < 4; ++kj)
#pragma unroll
      for (int nt = 0; nt < 4; ++nt)
        bXpf[kj][nt] = *(const s16x8*)&xt2[colbase + (size_t)(c0 + nt * 16 + l15) * 128 +
                                            kj * 32 + quad * 8];
  }
  __builtin_amdgcn_sched_barrier(0);

  // ---- P2: E GEMM (rows i0..i0+31 per wave, all j). D stays in registers.
  {
    const int i0 = wvid * 32;
    s16x8 aQ[2];
#pragma unroll
    for (int mt = 0; mt < 2; ++mt)
      aQ[mt] = *(const s16x8*)&sm.qt[(i0 + mt * 16 + l15) * 40 + quad * 8];
    f32x4 eacc[2][8];
#pragma unroll
    for (int mt = 0; mt < 2; ++mt)
#pragma unroll
      for (int nt = 0; nt < 8; ++nt) eacc[mt][nt] = {0.f, 0.f, 0.f, 0.f};
#pragma unroll
    for (int nt = 0; nt < 8; ++nt) {
      s16x8 bK = *(const s16x8*)&sm.kt[(nt * 16 + l15) * 40 + quad * 8];
      eacc[0][nt] = __builtin_amdgcn_mfma_f32_16x16x32_bf16(aQ[0], bK, eacc[0][nt], 0, 0, 0);
      eacc[1][nt] = __builtin_amdgcn_mfma_f32_16x16x32_bf16(aQ[1], bK, eacc[1][nt], 0, 0, 0);
    }
    // ---- P3: in-register softmax. Row i = i0+mt*16+quad*4+r lives in the 16 lanes
    // of one quad group (cols j = nt*16+l15). Diagonal mask, then 16-lane shfl reduce.
#pragma unroll
    for (int mt = 0; mt < 2; ++mt)
#pragma unroll
      for (int nt = 0; nt < 8; ++nt) {
        const int j = nt * 16 + l15;
#pragma unroll
        for (int r = 0; r < 4; ++r)
          if (j == i0 + mt * 16 + quad * 4 + r) eacc[mt][nt][r] = -__builtin_inff();
      }
#pragma unroll
    for (int mt = 0; mt < 2; ++mt)
#pragma unroll
      for (int r = 0; r < 4; ++r) {
        float mx = -__builtin_inff();
#pragma unroll
        for (int nt = 0; nt < 8; ++nt) mx = fmaxf(mx, eacc[mt][nt][r]);
        mx = fmaxf(mx, __shfl_xor(mx, 1));
        mx = fmaxf(mx, __shfl_xor(mx, 2));
        mx = fmaxf(mx, __shfl_xor(mx, 4));
        mx = fmaxf(mx, __shfl_xor(mx, 8));
        float s = 0.f;
#pragma unroll
        for (int nt = 0; nt < 8; ++nt) {
          float p = __expf(eacc[mt][nt][r] - mx);
          eacc[mt][nt][r] = p;
          s += p;
        }
        s += __shfl_xor(s, 1);
        s += __shfl_xor(s, 2);
        s += __shfl_xor(s, 4);
        s += __shfl_xor(s, 8);
        const float inv = 1.0f / s;
        const int i = i0 + mt * 16 + quad * 4 + r;
#pragma unroll
        for (int nt = 0; nt < 8; ++nt)
          sm.u.att[i * 136 + nt * 16 + l15] = f2b(eacc[mt][nt][r] * inv);
      }
  }
  __syncthreads();

  // ---- P4: Y GEMM. M=i(128), N=c(64/wave), K=j(128). A=att (LDS), B=bXpf (regs, R6).
  f32x4 yacc[8][4];
#pragma unroll
  for (int mt = 0; mt < 8; ++mt)
#pragma unroll
    for (int nt = 0; nt < 4; ++nt) yacc[mt][nt] = {0.f, 0.f, 0.f, 0.f};
  {
#pragma unroll
    for (int kj = 0; kj < 4; ++kj) {
      s16x8 aP[8];
#pragma unroll
      for (int mt = 0; mt < 8; ++mt)
        aP[mt] = *(const s16x8*)&sm.u.att[(mt * 16 + l15) * 136 + kj * 32 + quad * 8];
#pragma unroll
      for (int nt = 0; nt < 4; ++nt) {
#pragma unroll
        for (int mt = 0; mt < 8; ++mt)
          yacc[mt][nt] = __builtin_amdgcn_mfma_f32_16x16x32_bf16(aP[mt], bXpf[kj][nt],
                                                                 yacc[mt][nt], 0, 0, 0);
      }
    }
  }
  // ---- P5: store y in two c-halves via ybuf (aliases att; all A-reads done).
#pragma unroll 1
  for (int h2 = 0; h2 < 2; ++h2) {
    __syncthreads();
    if ((wvid >> 1) == h2) {
      const int clb = (wvid & 1) * 64;
#pragma unroll
      for (int mt = 0; mt < 8; ++mt)
#pragma unroll
        for (int nt = 0; nt < 4; ++nt) {
          const int cl = clb + nt * 16 + l15;
#pragma unroll
          for (int r = 0; r < 4; ++r)
            sm.u.att[(mt * 16 + quad * 4 + r) * 136 + cl] = f2b(yacc[mt][nt][r]);
        }
    }
    __syncthreads();
#pragma unroll
    for (int it = 0; it < 8; ++it) {
      int g = it * 256 + t;
      int i = g >> 4, cc = (g & 15) * 8;
      *(uint4*)&y[((size_t)(b * 128 + i) * 128 + w) * 256 + h2 * 128 + cc] =
          *(const uint4*)&sm.u.att[i * 136 + cc];
    }
  }
}

// ---------------- K2g: m97-style double-buffered LDS GEMM + x-prefetch (R3) ----------------
// out[b][co][h][w] = gamma*(Wv.Y + bv) + x.  Per block: 128co x 128w tile of one (b,h).
// Grid 2048. XCD pair-swizzle: bh = (bid>>4)*8 + (bid&7), mhalf = (bid>>3)&1 -> the two
// co-half blocks sharing one y slice land on the SAME XCD, 8 dispatch slots apart.
// A = wv[co][c], B = y[b][h][w][c] (row stride 512B). BK=64.
// LDS tiles [128 rows][64 c] bf16, XOR-swizzled: byte ^= ((row&7)<<4).
// Rule 21: global_load_lds writes LINEAR dest; swizzle applied to SOURCE addr + READ addr.
// R3: x epilogue operand prefetched into regs, 16 loads per kt step (overlaps main loop;
// per-kt __syncthreads vmcnt-drain guarantees completion before epilogue).
// R8 lesson: keep the scalar epilogue — its stores L2-merge to exactly out-size writes;
// a float4 LDS-bounce variant doubled HBM writes + 11M bank conflicts.

struct SmemG {
  unsigned short A[2][128 * 64];  // [buf][row=co][c'] swizzled, 16KB each
  unsigned short B[2][128 * 64];  // [buf][row=w][c']
};                                // 64KB total -> 2 blocks/CU

__global__ __launch_bounds__(256, 2)
void k2g(const unsigned short* __restrict__ y, const unsigned short* __restrict__ wv,
         const float* __restrict__ bv, const float* __restrict__ gamma,
         const float* __restrict__ x, float* __restrict__ out) {
  __shared__ SmemG sm;
  const int t = threadIdx.x;
  const int wv_id = t >> 6;
  const int lane = t & 63;
  const int l15 = lane & 15;
  const int quad = lane >> 4;
  // XCD pair-swizzle (bijective): paired co-halves -> same XCD (bid%8 preserved).
  const int mhalf = (blockIdx.x >> 3) & 1;
  const int bh = ((blockIdx.x >> 4) << 3) | (blockIdx.x & 7);
  const int b = bh >> 7, h = bh & 127;
  const unsigned short* gA = wv + mhalf * 128 * 256;      // 128 co rows
  const unsigned short* gB = y + (size_t)bh * 128 * 256;  // 128 w rows
  const int wr = wv_id >> 1;   // co 64-half within tile
  const int wc = wv_id & 1;    // w 64-half within tile

  f32x4 acc[4][4];
#pragma unroll
  for (int mt = 0; mt < 4; ++mt)
#pragma unroll
    for (int nt = 0; nt < 4; ++nt) acc[mt][nt] = {0.f, 0.f, 0.f, 0.f};
  float xpf[4][4][4];  // [mt][r][nt] epilogue x operand, prefetched in kt loop

  // prologue: stage K-chunk 0 into buf 0
  stage_tile(gA, sm.A[0], 0, wv_id, lane);
  stage_tile(gB, sm.B[0], 0, wv_id, lane);
  __syncthreads();  // drains vmcnt

#pragma unroll
  for (int kt = 0; kt < 4; ++kt) {
    const int cur = kt & 1;
    if (kt < 3) {  // issue next-chunk loads (async, vmcnt-tracked)
      stage_tile(gA, sm.A[cur ^ 1], (kt + 1) * 64, wv_id, lane);
      stage_tile(gB, sm.B[cur ^ 1], (kt + 1) * 64, wv_id, lane);
    }
    // x prefetch quarter (mt = kt, compile-time since loop is unrolled):
    // 16 loads in flight during this kt's MFMAs; drained by this kt's barrier.
    {
      const int mt = kt;
#pragma unroll
      for (int r = 0; r < 4; ++r) {
        const int co = mhalf * 128 + wr * 64 + mt * 16 + quad * 4 + r;
        const float* xp = x + ((size_t)(b * 256 + co) * 128 + h) * 128 + wc * 64 + l15;
#pragma unroll
        for (int nt = 0; nt < 4; ++nt) xpf[mt][r][nt] = xp[nt * 16];
      }
    }
    // compute current buffer: 2 k-substeps of 32, 16 MFMA each
#pragma unroll
    for (int ks = 0; ks < 2; ++ks) {
      s16x8 a[4], bb[4];
#pragma unroll
      for (int mt = 0; mt < 4; ++mt) {
        const int row = wr * 64 + mt * 16 + l15;
        const int col = (ks * 64 + quad * 16) ^ ((row & 7) << 4);
        a[mt] = *(const s16x8*)((const char*)&sm.A[cur][0] + row * 128 + col);
      }
#pragma unroll
      for (int nt = 0; nt < 4; ++nt) {
        const int row = wc * 64 + nt * 16 + l15;
        const int col = (ks * 64 + quad * 16) ^ ((row & 7) << 4);
        bb[nt] = *(const s16x8*)((const char*)&sm.B[cur][0] + row * 128 + col);
      }
#pragma unroll
      for (int nt = 0; nt < 4; ++nt)
#pragma unroll
        for (int mt = 0; mt < 4; ++mt)
          acc[mt][nt] = __builtin_amdgcn_mfma_f32_16x16x32_bf16(a[mt], bb[nt], acc[mt][nt], 0, 0, 0);
    }
    __syncthreads();  // staged buf ready; all reads of cur done before overwrite
  }

  // epilogue: out = gamma*(acc + bv) + x  (x already in regs -> store-only burst)
  const float g = gamma[0];
#pragma unroll
  for (int mt = 0; mt < 4; ++mt)
#pragma unroll
    for (int r = 0; r < 4; ++r) {
      const int co = mhalf * 128 + wr * 64 + mt * 16 + quad * 4 + r;
      const float bvv = bv[co];
      const size_t base = ((size_t)(b * 256 + co) * 128 + h) * 128;
#pragma unroll
      for (int nt = 0; nt < 4; ++nt) {
        const int wcol = wc * 64 + nt * 16 + l15;
        out[base + wcol] = g * (acc[mt][nt][r] + bvv) + xpf[mt][r][nt];
      }
    }
}

// ---------------- fallback path (round-1 verified, used only if ws too small) ----------------

struct SmemK1 {
  __hip_bfloat16 x[CH_][H_];
  float att[H_][130];
  union {
    struct { __hip_bfloat16 q[CQK_][H_]; __hip_bfloat16 k[CQK_][H_]; } qk;
    float vchunk[32][130];
  } s;
};

__device__ __forceinline__ void load_bf16x16(const __hip_bfloat16* p, float* f) {
  const uint4* p4 = (const uint4*)p;
  uint4 a = p4[0], b = p4[1];
  unsigned uu[8] = {a.x, a.y, a.z, a.w, b.x, b.y, b.z, b.w};
#pragma unroll
  for (int m = 0; m < 8; ++m) {
    f[2 * m] = __uint_as_float(uu[m] << 16);
    f[2 * m + 1] = __uint_as_float(uu[m] & 0xffff0000u);
  }
}

__global__ __launch_bounds__(256, 1)
void k1_attn(const float* __restrict__ x, const float* __restrict__ Wq,
             const float* __restrict__ bq, const float* __restrict__ Wk,
             const float* __restrict__ bk, const float* __restrict__ Wv,
             const float* __restrict__ bv, float* __restrict__ o_t) {
  __shared__ SmemK1 sm;
  const int t = threadIdx.x;
  const int b = blockIdx.x >> 7;
  const int w = blockIdx.x & 127;
  {
    const float* xb = x + (size_t)b * CH_ * H_ * W_ + w;
    const int h = t & 127;
    const int c0 = (t >> 7) * 128;
#pragma unroll 8
    for (int r = 0; r < 128; ++r) {
      const int c = c0 + r;
      sm.x[c][h] = __float2bfloat16(xb[(size_t)(c * H_ + h) * W_]);
    }
  }
  __syncthreads();
  {
    const int qc = t >> 3;
    const int i0 = (t & 7) << 4;
    float qa[16], ka[16];
    const float bqv = bq[qc], bkv = bk[qc];
#pragma unroll
    for (int u = 0; u < 16; ++u) { qa[u] = bqv; ka[u] = bkv; }
    const float* wqr = Wq + qc * CH_;
    const float* wkr = Wk + qc * CH_;
    for (int c = 0; c < CH_; c += 4) {
      const float4 wq4 = *(const float4*)(wqr + c);
      const float4 wk4 = *(const float4*)(wkr + c);
      const float wqs[4] = {wq4.x, wq4.y, wq4.z, wq4.w};
      const float wks[4] = {wk4.x, wk4.y, wk4.z, wk4.w};
#pragma unroll
      for (int cc = 0; cc < 4; ++cc) {
        float xf[16];
        load_bf16x16(&sm.x[c + cc][i0], xf);
#pragma unroll
        for (int u = 0; u < 16; ++u) {
          qa[u] += wqs[cc] * xf[u];
          ka[u] += wks[cc] * xf[u];
        }
      }
    }
#pragma unroll
    for (int u = 0; u < 16; ++u) {
      sm.s.qk.q[qc][i0 + u] = __float2bfloat16(qa[u]);
      sm.s.qk.k[qc][i0 + u] = __float2bfloat16(ka[u]);
    }
  }
  __syncthreads();
  {
    const int i = t >> 1;
    const int j0 = (t & 1) << 6;
    float qreg[32];
#pragma unroll
    for (int qc = 0; qc < 32; ++qc) qreg[qc] = __bfloat162float(sm.s.qk.q[qc][i]);
    float e[64];
#pragma unroll
    for (int u = 0; u < 64; ++u) e[u] = 0.0f;
    for (int qc = 0; qc < 32; ++qc) {
#pragma unroll
      for (int jc = 0; jc < 4; ++jc) {
        float kf[16];
        load_bf16x16(&sm.s.qk.k[qc][j0 + jc * 16], kf);
#pragma unroll
        for (int u = 0; u < 16; ++u) e[jc * 16 + u] += qreg[qc] * kf[u];
      }
    }
    if (i >= j0 && i < j0 + 64) e[i - j0] = -__builtin_inff();
    float m = -__builtin_inff();
#pragma unroll
    for (int u = 0; u < 64; ++u) m = fmaxf(m, e[u]);
    m = fmaxf(m, __shfl_xor(m, 1));
    float ssum = 0.0f;
#pragma unroll
    for (int u = 0; u < 64; ++u) { e[u] = __expf(e[u] - m); ssum += e[u]; }
    ssum += __shfl_xor(ssum, 1);
    const float inv = 1.0f / ssum;
#pragma unroll
    for (int u = 0; u < 64; u += 2)
      *(float2*)&sm.att[i][j0 + u] = make_float2(e[u] * inv, e[u + 1] * inv);
  }
  __syncthreads();
  const int vcc = t >> 3;
  const int vj0 = (t & 7) << 4;
  const int ai0 = (t >> 3) << 2;
  const int acc0 = (t & 7) << 2;
  for (int ch = 0; ch < 8; ++ch) {
    {
      const int cg = ch * 32 + vcc;
      float acc[16];
      const float bvv = bv[cg];
#pragma unroll
      for (int u = 0; u < 16; ++u) acc[u] = bvv;
      const float* wvr = Wv + (size_t)cg * CH_;
      for (int c = 0; c < CH_; c += 4) {
        const float4 w4 = *(const float4*)(wvr + c);
        const float ws4[4] = {w4.x, w4.y, w4.z, w4.w};
#pragma unroll
        for (int cc = 0; cc < 4; ++cc) {
          float xf[16];
          load_bf16x16(&sm.x[c + cc][vj0], xf);
#pragma unroll
          for (int u = 0; u < 16; ++u) acc[u] += ws4[cc] * xf[u];
        }
      }
#pragma unroll
      for (int m2 = 0; m2 < 8; ++m2)
        *(float2*)&sm.s.vchunk[vcc][vj0 + 2 * m2] = make_float2(acc[2 * m2], acc[2 * m2 + 1]);
    }
    __syncthreads();
    {
      float oacc[4][4];
#pragma unroll
      for (int s2 = 0; s2 < 4; ++s2)
#pragma unroll
        for (int u = 0; u < 4; ++u) oacc[s2][u] = 0.0f;
#pragma unroll 4
      for (int j = 0; j < H_; j += 2) {
        float2 av[4], vv[4];
#pragma unroll
        for (int u = 0; u < 4; ++u) av[u] = *(const float2*)&sm.att[ai0 + u][j];
#pragma unroll
        for (int s2 = 0; s2 < 4; ++s2) vv[s2] = *(const float2*)&sm.s.vchunk[acc0 + s2][j];
#pragma unroll
        for (int s2 = 0; s2 < 4; ++s2)
#pragma unroll
          for (int u = 0; u < 4; ++u)
            oacc[s2][u] += vv[s2].x * av[u].x + vv[s2].y * av[u].y;
      }
#pragma unroll
      for (int s2 = 0; s2 < 4; ++s2) {
        const int cg = ch * 32 + acc0 + s2;
        float4 st;
        st.x = oacc[s2][0]; st.y = oacc[s2][1]; st.z = oacc[s2][2]; st.w = oacc[s2][3];
        *(float4*)&o_t[(((size_t)b * CH_ + cg) * W_ + w) * H_ + ai0] = st;
      }
    }
    __syncthreads();
  }
}

__global__ __launch_bounds__(256)
void k2_epi(const float* __restrict__ o_t, const float* __restrict__ x,
            const float* __restrict__ gamma, float* __restrict__ out) {
  const int pr = blockIdx.x % 10;
  const int plane = blockIdx.x / 10;
  const int rT[10] = {0, 0, 0, 0, 1, 1, 1, 2, 2, 3};
  const int sT[10] = {0, 1, 2, 3, 1, 2, 3, 2, 3, 3};
  const int r = rT[pr], s = sT[pr];
  __shared__ float t1[32][33];
  __shared__ float t2[32][33];
  const int t = threadIdx.x;
  const size_t pbase = (size_t)plane * (H_ * W_);
  const float* ob = o_t + pbase;
#pragma unroll
  for (int ii = 0; ii < 4; ++ii) {
    const int idx = ii * 256 + t;
    const int ww = idx >> 5, hh = idx & 31;
    t1[ww][hh] = ob[(s * 32 + ww) * H_ + (r * 32 + hh)];
    if (r != s) t2[ww][hh] = ob[(r * 32 + ww) * H_ + (s * 32 + hh)];
  }
  __syncthreads();
  const float g = gamma[0];
#pragma unroll
  for (int ii = 0; ii < 4; ++ii) {
    const int idx = ii * 256 + t;
    const int hh = idx >> 5, ww = idx & 31;
    const size_t o1 = pbase + (size_t)(r * 32 + hh) * W_ + (s * 32 + ww);
    out[o1] = g * t1[ww][hh] + x[o1];
    if (r != s) {
      const size_t o2 = pbase + (size_t)(s * 32 + hh) * W_ + (r * 32 + ww);
      out[o2] = g * t2[ww][hh] + x[o2];
    }
  }
}

// ---------------- launch ----------------

extern "C" void kernel_launch(void* const* d_in, const int* in_sizes, int n_in,
                              void* d_out, int out_size, void* d_ws, size_t ws_size,
                              hipStream_t stream) {
  const float* x     = (const float*)d_in[0];
  const float* Wq    = (const float*)d_in[1];
  const float* bq    = (const float*)d_in[2];
  const float* Wk    = (const float*)d_in[3];
  const float* bk    = (const float*)d_in[4];
  const float* Wv    = (const float*)d_in[5];
  const float* bv    = (const float*)d_in[6];
  const float* gamma = (const float*)d_in[7];
  float* out = (float*)d_out;

  const size_t XT   = (size_t)B_ * W_ * H_ * CH_ * 2;  // 64 MiB bf16
  const size_t YT   = XT;                              // 64 MiB bf16
  const size_t WQKB = 64 * 256 * 2;
  const size_t WVB  = 256 * 256 * 2;
  const size_t FAST_WS = XT + YT + WQKB + WVB;

  if (ws_size >= FAST_WS) {
    unsigned short* xt  = (unsigned short*)d_ws;
    unsigned short* yb  = (unsigned short*)((char*)d_ws + XT);
    unsigned short* wqk = (unsigned short*)((char*)d_ws + XT + YT);
    unsigned short* wvb = (unsigned short*)((char*)d_ws + XT + YT + WQKB);
    // xt2 lives in d_out (64 of 128 MiB): dead before k2g overwrites out.
    unsigned short* xt2 = (unsigned short*)d_out;
    hipLaunchKernelGGL(kw_pack, dim3(320), dim3(256), 0, stream, Wq, Wk, Wv, wqk, wvb);
    hipLaunchKernelGGL(k0_xpose, dim3(B_ * H_), dim3(256), 0, stream, x, xt);
    hipLaunchKernelGGL(k0b_xpose, dim3(B_ * W_), dim3(256), 0, stream, xt, xt2);
    hipLaunchKernelGGL(k1y, dim3(B_ * W_), dim3(256), 0, stream,
                       xt, xt2, wqk, bq, bk, yb);
    hipLaunchKernelGGL(k2g, dim3(B_ * H_ * 2), dim3(256), 0, stream,
                       yb, wvb, bv, gamma, x, out);
  } else {
    const size_t OT_F = (size_t)B_ * CH_ * H_ * W_ * sizeof(float);
    float* o_t = (ws_size >= OT_F) ? (float*)d_ws : out;
    hipLaunchKernelGGL(k1_attn, dim3(B_ * W_), dim3(256), 0, stream,
                       x, Wq, bq, Wk, bk, Wv, bv, o_t);
    hipLaunchKernelGGL(k2_epi, dim3((B_ * CH_) * 10), dim3(256), 0, stream,
                       o_t, x, gamma, out);
  }
}

// Round 10
// 343.362 us; speedup vs baseline: 1.2055x; 1.0883x over previous
//
#include <hip/hip_runtime.h>
#include <hip/hip_bf16.h>

#define B_   8
#define CH_  256
#define CQK_ 32
#define H_   128
#define W_   128

typedef __attribute__((ext_vector_type(8))) short s16x8;
typedef __attribute__((ext_vector_type(4))) float f32x4;
typedef __attribute__((ext_vector_type(4))) unsigned short u16x4;

__device__ __forceinline__ unsigned short f2b(float f) {
  __hip_bfloat16 h = __float2bfloat16(f);
  return *(unsigned short*)&h;
}
__device__ __forceinline__ float b2f(unsigned short u) {
  return __uint_as_float(((unsigned)u) << 16);
}

// ---------------- fast path ----------------
// Pipeline (R10): kw_pack -> k0_xpose (xt[b][w][h][c]) -> k1y (QK, E, softmax, Y=att*X' -> y)
//   -> k2g (out = gamma*(Wv.Y + bv) + x).
// R10: k0b ELIMINATED. k1y P4's B-fragments (formerly xt2[b][w][c][h] global reads) are
// built in-register during P1: wave wvid's P4 c-range [wvid*64,+64) == P1 staged chunk
// kc==wvid, so 128 ds_read_u16 from the staged LDS tile (transpose-read via the rule-21
// swizzle algebra, valid at 2B granularity) replace the k0b kernel + 67MB xt2 traffic.
// R5 lesson: out layout forces block-per-(b,h) -> y intermediate is structural.
// R7 lesson: BK=32 + launch_bounds(,4) regressed (VGPR starvation + 2x barrier drains).
// R8 lesson: scalar k2g epilogue stores already L2-merge to exactly out-size writes.

__global__ void kw_pack(const float* __restrict__ Wq, const float* __restrict__ Wk,
                        const float* __restrict__ Wv, unsigned short* __restrict__ wqk,
                        unsigned short* __restrict__ wv) {
  int idx = blockIdx.x * 256 + threadIdx.x;
  if (idx < 64 * 256) {
    int qc = idx >> 8, c = idx & 255;
    wqk[idx] = f2b(qc < 32 ? Wq[qc * 256 + c] : Wk[(qc - 32) * 256 + c]);
  } else {
    int i2 = idx - 64 * 256;  // < 65536
    wv[i2] = f2b(Wv[i2]);
  }
}

// K0: x[b][c][h][w] fp32 -> xt[b][w][h][c] bf16. Block per (b,h). (verified R2)
__global__ __launch_bounds__(256) void k0_xpose(const float* __restrict__ x,
                                                unsigned short* __restrict__ xt) {
  __shared__ unsigned short st[256 * 137];
  const int t = threadIdx.x;
  const int b = blockIdx.x >> 7;
  const int h = blockIdx.x & 127;
  const float* xin = x + ((size_t)b * 256 * 128 + h) * 128;
  const int w = t & 127, chalf = t >> 7;
#pragma unroll 8
  for (int it = 0; it < 128; ++it) {
    int c = it * 2 + chalf;
    st[c * 137 + w] = f2b(xin[(size_t)c * 16384 + w]);
  }
  __syncthreads();
  unsigned short* xo = xt + ((size_t)b * 128 * 128 + h) * 256;
  const int cl = t & 127, whalf = t >> 7;
#pragma unroll 8
  for (int it = 0; it < 64; ++it) {
    int wr = it * 2 + whalf;
    unsigned v = (unsigned)st[(2 * cl) * 137 + wr] |
                 ((unsigned)st[(2 * cl + 1) * 137 + wr] << 16);
    *(unsigned*)&xo[(size_t)wr * 32768 + 2 * cl] = v;
  }
}

// ---- shared staging helper (verified R2/R4): stage one 16KB tile
// (128 rows x 64 bf16) from gsrc (row stride 256 elem) k-slice k0 into linear LDS,
// with inverse-XOR-swizzled SOURCE so that swizzled READS (byte ^ ((row&7)<<4))
// return linear data (rule 21 pairing). Valid at 2-byte granularity (XOR bits>=4).
__device__ __forceinline__ void gld_lds16(const unsigned short* g, unsigned short* l) {
  __builtin_amdgcn_global_load_lds(
      (const __attribute__((address_space(1))) void*)g,
      (__attribute__((address_space(3))) void*)l, 16, 0, 0);
}

__device__ __forceinline__ void stage_tile(const unsigned short* __restrict__ gsrc,
                                           unsigned short* lds, int k0,
                                           int wv_id, int lane) {
#pragma unroll
  for (int i = 0; i < 4; ++i) {
    const int chunk = wv_id * 4 + i;
    const int L = chunk * 1024 + lane * 16;       // linear LDS byte this lane fills
    const int row = L >> 7;                       // 128B per row
    const int sb = L & 127;
    const int srcb = sb ^ ((row & 7) << 4);       // inverse-swizzled source slot
    gld_lds16(gsrc + row * 256 + k0 + (srcb >> 1), lds + chunk * 512);
  }
}

// K1y: per (b,w): P1 QK GEMM (B staged via global_load_lds dbuf; P4 B-frags
// transpose-read from chunk kc==wvid), P2 E GEMM, P3 in-register softmax,
// P4 Y = att * X' (B from bXpf regs), P5 y[b][h][w][c] bf16 out.
struct SmemY {
  unsigned short qt[128 * 40];     // [h][qc]  10240 B
  unsigned short kt[128 * 40];     //          10240 B
  union {
    unsigned short att[128 * 136]; // [i][j] bf16; reused as ybuf[i][c-half] 34816 B
    unsigned short xstage[2][128 * 64]; // P1 staging dbuf (dead before att written)
  } u;
};                               // total 55296 B -> 2 blocks/CU

__global__ __launch_bounds__(256, 2)
void k1y(const unsigned short* __restrict__ xt, const unsigned short* __restrict__ wqk,
         const float* __restrict__ bq, const float* __restrict__ bk,
         unsigned short* __restrict__ y) {
  __shared__ SmemY sm;
  const int t = threadIdx.x;
  const int wvid = t >> 6;
  const int lane = t & 63;
  const int l15 = lane & 15;
  const int quad = lane >> 4;
  const int b = blockIdx.x >> 7;
  const int w = blockIdx.x & 127;
  const size_t colbase = ((size_t)b * 128 + w) * 32768;

  // P4 B-fragments, built during P1 from the staged chunk kc==wvid (R10).
  s16x8 bXpf[4][4];

  // ---- P1: QK GEMM. M=qc(16/wave), N=h(128), K=c(256). B staged via dbuf gld_lds.
  {
    const int qc0 = wvid * 16;
    f32x4 acc[8];
#pragma unroll
    for (int nt = 0; nt < 8; ++nt) acc[nt] = {0.f, 0.f, 0.f, 0.f};
    const unsigned short* arow = wqk + (qc0 + l15) * 256 + quad * 8;
    const unsigned short* gcol = xt + colbase;  // 128 h-rows, stride 256 elem
    stage_tile(gcol, sm.u.xstage[0], 0, wvid, lane);
    __syncthreads();  // drains vmcnt
#pragma unroll
    for (int kc = 0; kc < 4; ++kc) {
      const int cur = kc & 1;
      if (kc < 3) stage_tile(gcol, sm.u.xstage[cur ^ 1], (kc + 1) * 64, wvid, lane);
      // R10: wave wvid's P4 B-data (c in [wvid*64,+64), all h) lives in THIS chunk.
      // Transpose-read it into regs: frag (kj,nt) elem e = chunk[row=kj*32+quad*8+e]
      // [col_e=nt*16+l15], byte = row*128 + ((col_e*2) ^ ((row&7)<<4)). Uniform branch.
      if (kc == wvid) {
        const char* chunkp = (const char*)sm.u.xstage[cur];
#pragma unroll
        for (int kj = 0; kj < 4; ++kj)
#pragma unroll
          for (int nt = 0; nt < 4; ++nt)
#pragma unroll
            for (int e = 0; e < 8; ++e) {
              const int row = kj * 32 + quad * 8 + e;
              const int cb = ((nt * 16 + l15) * 2) ^ ((row & 7) << 4);
              bXpf[kj][nt][e] =
                  *(const short*)(chunkp + row * 128 + cb);
            }
      }
#pragma unroll
      for (int kk2 = 0; kk2 < 2; ++kk2) {
        s16x8 a = *(const s16x8*)(arow + (kc * 2 + kk2) * 32);
#pragma unroll
        for (int nt = 0; nt < 8; ++nt) {
          const int row = nt * 16 + l15;
          const int col = (kk2 * 64 + quad * 16) ^ ((row & 7) << 4);
          s16x8 bb = *(const s16x8*)((const char*)sm.u.xstage[cur] + row * 128 + col);
          acc[nt] = __builtin_amdgcn_mfma_f32_16x16x32_bf16(a, bb, acc[nt], 0, 0, 0);
        }
      }
      __syncthreads();  // staged buf ready; all reads of cur done before overwrite
    }
    const float* bp = (wvid < 2) ? bq : bk;
    const int qcl = qc0 & 16;
    float bias[4];
#pragma unroll
    for (int r = 0; r < 4; ++r) bias[r] = bp[qcl + quad * 4 + r];
    unsigned short* dst = (wvid < 2) ? sm.qt : sm.kt;
#pragma unroll
    for (int nt = 0; nt < 8; ++nt) {
      int h = nt * 16 + l15;
      u16x4 pk;
#pragma unroll
      for (int r = 0; r < 4; ++r) pk[r] = f2b(acc[nt][r] + bias[r]);
      *(u16x4*)&dst[h * 40 + qcl + quad * 4] = pk;
    }
  }
  __syncthreads();

  // ---- P2: E GEMM (rows i0..i0+31 per wave, all j). D stays in registers.
  {
    const int i0 = wvid * 32;
    s16x8 aQ[2];
#pragma unroll
    for (int mt = 0; mt < 2; ++mt)
      aQ[mt] = *(const s16x8*)&sm.qt[(i0 + mt * 16 + l15) * 40 + quad * 8];
    f32x4 eacc[2][8];
#pragma unroll
    for (int mt = 0; mt < 2; ++mt)
#pragma unroll
      for (int nt = 0; nt < 8; ++nt) eacc[mt][nt] = {0.f, 0.f, 0.f, 0.f};
#pragma unroll
    for (int nt = 0; nt < 8; ++nt) {
      s16x8 bK = *(const s16x8*)&sm.kt[(nt * 16 + l15) * 40 + quad * 8];
      eacc[0][nt] = __builtin_amdgcn_mfma_f32_16x16x32_bf16(aQ[0], bK, eacc[0][nt], 0, 0, 0);
      eacc[1][nt] = __builtin_amdgcn_mfma_f32_16x16x32_bf16(aQ[1], bK, eacc[1][nt], 0, 0, 0);
    }
    // ---- P3: in-register softmax. Row i = i0+mt*16+quad*4+r lives in the 16 lanes
    // of one quad group (cols j = nt*16+l15). Diagonal mask, then 16-lane shfl reduce.
#pragma unroll
    for (int mt = 0; mt < 2; ++mt)
#pragma unroll
      for (int nt = 0; nt < 8; ++nt) {
        const int j = nt * 16 + l15;
#pragma unroll
        for (int r = 0; r < 4; ++r)
          if (j == i0 + mt * 16 + quad * 4 + r) eacc[mt][nt][r] = -__builtin_inff();
      }
#pragma unroll
    for (int mt = 0; mt < 2; ++mt)
#pragma unroll
      for (int r = 0; r < 4; ++r) {
        float mx = -__builtin_inff();
#pragma unroll
        for (int nt = 0; nt < 8; ++nt) mx = fmaxf(mx, eacc[mt][nt][r]);
        mx = fmaxf(mx, __shfl_xor(mx, 1));
        mx = fmaxf(mx, __shfl_xor(mx, 2));
        mx = fmaxf(mx, __shfl_xor(mx, 4));
        mx = fmaxf(mx, __shfl_xor(mx, 8));
        float s = 0.f;
#pragma unroll
        for (int nt = 0; nt < 8; ++nt) {
          float p = __expf(eacc[mt][nt][r] - mx);
          eacc[mt][nt][r] = p;
          s += p;
        }
        s += __shfl_xor(s, 1);
        s += __shfl_xor(s, 2);
        s += __shfl_xor(s, 4);
        s += __shfl_xor(s, 8);
        const float inv = 1.0f / s;
        const int i = i0 + mt * 16 + quad * 4 + r;
#pragma unroll
        for (int nt = 0; nt < 8; ++nt)
          sm.u.att[i * 136 + nt * 16 + l15] = f2b(eacc[mt][nt][r] * inv);
      }
  }
  __syncthreads();

  // ---- P4: Y GEMM. M=i(128), N=c(64/wave), K=j(128). A=att (LDS), B=bXpf (regs).
  f32x4 yacc[8][4];
#pragma unroll
  for (int mt = 0; mt < 8; ++mt)
#pragma unroll
    for (int nt = 0; nt < 4; ++nt) yacc[mt][nt] = {0.f, 0.f, 0.f, 0.f};
  {
#pragma unroll
    for (int kj = 0; kj < 4; ++kj) {
      s16x8 aP[8];
#pragma unroll
      for (int mt = 0; mt < 8; ++mt)
        aP[mt] = *(const s16x8*)&sm.u.att[(mt * 16 + l15) * 136 + kj * 32 + quad * 8];
#pragma unroll
      for (int nt = 0; nt < 4; ++nt) {
#pragma unroll
        for (int mt = 0; mt < 8; ++mt)
          yacc[mt][nt] = __builtin_amdgcn_mfma_f32_16x16x32_bf16(aP[mt], bXpf[kj][nt],
                                                                 yacc[mt][nt], 0, 0, 0);
      }
    }
  }
  // ---- P5: store y in two c-halves via ybuf (aliases att; all A-reads done).
#pragma unroll 1
  for (int h2 = 0; h2 < 2; ++h2) {
    __syncthreads();
    if ((wvid >> 1) == h2) {
      const int clb = (wvid & 1) * 64;
#pragma unroll
      for (int mt = 0; mt < 8; ++mt)
#pragma unroll
        for (int nt = 0; nt < 4; ++nt) {
          const int cl = clb + nt * 16 + l15;
#pragma unroll
          for (int r = 0; r < 4; ++r)
            sm.u.att[(mt * 16 + quad * 4 + r) * 136 + cl] = f2b(yacc[mt][nt][r]);
        }
    }
    __syncthreads();
#pragma unroll
    for (int it = 0; it < 8; ++it) {
      int g = it * 256 + t;
      int i = g >> 4, cc = (g & 15) * 8;
      *(uint4*)&y[((size_t)(b * 128 + i) * 128 + w) * 256 + h2 * 128 + cc] =
          *(const uint4*)&sm.u.att[i * 136 + cc];
    }
  }
}

// ---------------- K2g: m97-style double-buffered LDS GEMM + x-prefetch (R3) ----------------
// out[b][co][h][w] = gamma*(Wv.Y + bv) + x.  Per block: 128co x 128w tile of one (b,h).
// Grid 2048. XCD pair-swizzle: bh = (bid>>4)*8 + (bid&7), mhalf = (bid>>3)&1 -> the two
// co-half blocks sharing one y slice land on the SAME XCD, 8 dispatch slots apart.
// A = wv[co][c], B = y[b][h][w][c] (row stride 512B). BK=64.
// LDS tiles [128 rows][64 c] bf16, XOR-swizzled: byte ^= ((row&7)<<4).
// Rule 21: global_load_lds writes LINEAR dest; swizzle applied to SOURCE addr + READ addr.
// R3: x epilogue operand prefetched into regs, 16 loads per kt step (overlaps main loop;
// per-kt __syncthreads vmcnt-drain guarantees completion before epilogue).
// R8 lesson: keep the scalar epilogue — its stores L2-merge to exactly out-size writes.

struct SmemG {
  unsigned short A[2][128 * 64];  // [buf][row=co][c'] swizzled, 16KB each
  unsigned short B[2][128 * 64];  // [buf][row=w][c']
};                                // 64KB total -> 2 blocks/CU

__global__ __launch_bounds__(256, 2)
void k2g(const unsigned short* __restrict__ y, const unsigned short* __restrict__ wv,
         const float* __restrict__ bv, const float* __restrict__ gamma,
         const float* __restrict__ x, float* __restrict__ out) {
  __shared__ SmemG sm;
  const int t = threadIdx.x;
  const int wv_id = t >> 6;
  const int lane = t & 63;
  const int l15 = lane & 15;
  const int quad = lane >> 4;
  // XCD pair-swizzle (bijective): paired co-halves -> same XCD (bid%8 preserved).
  const int mhalf = (blockIdx.x >> 3) & 1;
  const int bh = ((blockIdx.x >> 4) << 3) | (blockIdx.x & 7);
  const int b = bh >> 7, h = bh & 127;
  const unsigned short* gA = wv + mhalf * 128 * 256;      // 128 co rows
  const unsigned short* gB = y + (size_t)bh * 128 * 256;  // 128 w rows
  const int wr = wv_id >> 1;   // co 64-half within tile
  const int wc = wv_id & 1;    // w 64-half within tile

  f32x4 acc[4][4];
#pragma unroll
  for (int mt = 0; mt < 4; ++mt)
#pragma unroll
    for (int nt = 0; nt < 4; ++nt) acc[mt][nt] = {0.f, 0.f, 0.f, 0.f};
  float xpf[4][4][4];  // [mt][r][nt] epilogue x operand, prefetched in kt loop

  // prologue: stage K-chunk 0 into buf 0
  stage_tile(gA, sm.A[0], 0, wv_id, lane);
  stage_tile(gB, sm.B[0], 0, wv_id, lane);
  __syncthreads();  // drains vmcnt

#pragma unroll
  for (int kt = 0; kt < 4; ++kt) {
    const int cur = kt & 1;
    if (kt < 3) {  // issue next-chunk loads (async, vmcnt-tracked)
      stage_tile(gA, sm.A[cur ^ 1], (kt + 1) * 64, wv_id, lane);
      stage_tile(gB, sm.B[cur ^ 1], (kt + 1) * 64, wv_id, lane);
    }
    // x prefetch quarter (mt = kt, compile-time since loop is unrolled):
    // 16 loads in flight during this kt's MFMAs; drained by this kt's barrier.
    {
      const int mt = kt;
#pragma unroll
      for (int r = 0; r < 4; ++r) {
        const int co = mhalf * 128 + wr * 64 + mt * 16 + quad * 4 + r;
        const float* xp = x + ((size_t)(b * 256 + co) * 128 + h) * 128 + wc * 64 + l15;
#pragma unroll
        for (int nt = 0; nt < 4; ++nt) xpf[mt][r][nt] = xp[nt * 16];
      }
    }
    // compute current buffer: 2 k-substeps of 32, 16 MFMA each
#pragma unroll
    for (int ks = 0; ks < 2; ++ks) {
      s16x8 a[4], bb[4];
#pragma unroll
      for (int mt = 0; mt < 4; ++mt) {
        const int row = wr * 64 + mt * 16 + l15;
        const int col = (ks * 64 + quad * 16) ^ ((row & 7) << 4);
        a[mt] = *(const s16x8*)((const char*)&sm.A[cur][0] + row * 128 + col);
      }
#pragma unroll
      for (int nt = 0; nt < 4; ++nt) {
        const int row = wc * 64 + nt * 16 + l15;
        const int col = (ks * 64 + quad * 16) ^ ((row & 7) << 4);
        bb[nt] = *(const s16x8*)((const char*)&sm.B[cur][0] + row * 128 + col);
      }
#pragma unroll
      for (int nt = 0; nt < 4; ++nt)
#pragma unroll
        for (int mt = 0; mt < 4; ++mt)
          acc[mt][nt] = __builtin_amdgcn_mfma_f32_16x16x32_bf16(a[mt], bb[nt], acc[mt][nt], 0, 0, 0);
    }
    __syncthreads();  // staged buf ready; all reads of cur done before overwrite
  }

  // epilogue: out = gamma*(acc + bv) + x  (x already in regs -> store-only burst)
  const float g = gamma[0];
#pragma unroll
  for (int mt = 0; mt < 4; ++mt)
#pragma unroll
    for (int r = 0; r < 4; ++r) {
      const int co = mhalf * 128 + wr * 64 + mt * 16 + quad * 4 + r;
      const float bvv = bv[co];
      const size_t base = ((size_t)(b * 256 + co) * 128 + h) * 128;
#pragma unroll
      for (int nt = 0; nt < 4; ++nt) {
        const int wcol = wc * 64 + nt * 16 + l15;
        out[base + wcol] = g * (acc[mt][nt][r] + bvv) + xpf[mt][r][nt];
      }
    }
}

// ---------------- fallback path (round-1 verified, used only if ws too small) ----------------

struct SmemK1 {
  __hip_bfloat16 x[CH_][H_];
  float att[H_][130];
  union {
    struct { __hip_bfloat16 q[CQK_][H_]; __hip_bfloat16 k[CQK_][H_]; } qk;
    float vchunk[32][130];
  } s;
};

__device__ __forceinline__ void load_bf16x16(const __hip_bfloat16* p, float* f) {
  const uint4* p4 = (const uint4*)p;
  uint4 a = p4[0], b = p4[1];
  unsigned uu[8] = {a.x, a.y, a.z, a.w, b.x, b.y, b.z, b.w};
#pragma unroll
  for (int m = 0; m < 8; ++m) {
    f[2 * m] = __uint_as_float(uu[m] << 16);
    f[2 * m + 1] = __uint_as_float(uu[m] & 0xffff0000u);
  }
}

__global__ __launch_bounds__(256, 1)
void k1_attn(const float* __restrict__ x, const float* __restrict__ Wq,
             const float* __restrict__ bq, const float* __restrict__ Wk,
             const float* __restrict__ bk, const float* __restrict__ Wv,
             const float* __restrict__ bv, float* __restrict__ o_t) {
  __shared__ SmemK1 sm;
  const int t = threadIdx.x;
  const int b = blockIdx.x >> 7;
  const int w = blockIdx.x & 127;
  {
    const float* xb = x + (size_t)b * CH_ * H_ * W_ + w;
    const int h = t & 127;
    const int c0 = (t >> 7) * 128;
#pragma unroll 8
    for (int r = 0; r < 128; ++r) {
      const int c = c0 + r;
      sm.x[c][h] = __float2bfloat16(xb[(size_t)(c * H_ + h) * W_]);
    }
  }
  __syncthreads();
  {
    const int qc = t >> 3;
    const int i0 = (t & 7) << 4;
    float qa[16], ka[16];
    const float bqv = bq[qc], bkv = bk[qc];
#pragma unroll
    for (int u = 0; u < 16; ++u) { qa[u] = bqv; ka[u] = bkv; }
    const float* wqr = Wq + qc * CH_;
    const float* wkr = Wk + qc * CH_;
    for (int c = 0; c < CH_; c += 4) {
      const float4 wq4 = *(const float4*)(wqr + c);
      const float4 wk4 = *(const float4*)(wkr + c);
      const float wqs[4] = {wq4.x, wq4.y, wq4.z, wq4.w};
      const float wks[4] = {wk4.x, wk4.y, wk4.z, wk4.w};
#pragma unroll
      for (int cc = 0; cc < 4; ++cc) {
        float xf[16];
        load_bf16x16(&sm.x[c + cc][i0], xf);
#pragma unroll
        for (int u = 0; u < 16; ++u) {
          qa[u] += wqs[cc] * xf[u];
          ka[u] += wks[cc] * xf[u];
        }
      }
    }
#pragma unroll
    for (int u = 0; u < 16; ++u) {
      sm.s.qk.q[qc][i0 + u] = __float2bfloat16(qa[u]);
      sm.s.qk.k[qc][i0 + u] = __float2bfloat16(ka[u]);
    }
  }
  __syncthreads();
  {
    const int i = t >> 1;
    const int j0 = (t & 1) << 6;
    float qreg[32];
#pragma unroll
    for (int qc = 0; qc < 32; ++qc) qreg[qc] = __bfloat162float(sm.s.qk.q[qc][i]);
    float e[64];
#pragma unroll
    for (int u = 0; u < 64; ++u) e[u] = 0.0f;
    for (int qc = 0; qc < 32; ++qc) {
#pragma unroll
      for (int jc = 0; jc < 4; ++jc) {
        float kf[16];
        load_bf16x16(&sm.s.qk.k[qc][j0 + jc * 16], kf);
#pragma unroll
        for (int u = 0; u < 16; ++u) e[jc * 16 + u] += qreg[qc] * kf[u];
      }
    }
    if (i >= j0 && i < j0 + 64) e[i - j0] = -__builtin_inff();
    float m = -__builtin_inff();
#pragma unroll
    for (int u = 0; u < 64; ++u) m = fmaxf(m, e[u]);
    m = fmaxf(m, __shfl_xor(m, 1));
    float ssum = 0.0f;
#pragma unroll
    for (int u = 0; u < 64; ++u) { e[u] = __expf(e[u] - m); ssum += e[u]; }
    ssum += __shfl_xor(ssum, 1);
    const float inv = 1.0f / ssum;
#pragma unroll
    for (int u = 0; u < 64; u += 2)
      *(float2*)&sm.att[i][j0 + u] = make_float2(e[u] * inv, e[u + 1] * inv);
  }
  __syncthreads();
  const int vcc = t >> 3;
  const int vj0 = (t & 7) << 4;
  const int ai0 = (t >> 3) << 2;
  const int acc0 = (t & 7) << 2;
  for (int ch = 0; ch < 8; ++ch) {
    {
      const int cg = ch * 32 + vcc;
      float acc[16];
      const float bvv = bv[cg];
#pragma unroll
      for (int u = 0; u < 16; ++u) acc[u] = bvv;
      const float* wvr = Wv + (size_t)cg * CH_;
      for (int c = 0; c < CH_; c += 4) {
        const float4 w4 = *(const float4*)(wvr + c);
        const float ws4[4] = {w4.x, w4.y, w4.z, w4.w};
#pragma unroll
        for (int cc = 0; cc < 4; ++cc) {
          float xf[16];
          load_bf16x16(&sm.x[c + cc][vj0], xf);
#pragma unroll
          for (int u = 0; u < 16; ++u) acc[u] += ws4[cc] * xf[u];
        }
      }
#pragma unroll
      for (int m2 = 0; m2 < 8; ++m2)
        *(float2*)&sm.s.vchunk[vcc][vj0 + 2 * m2] = make_float2(acc[2 * m2], acc[2 * m2 + 1]);
    }
    __syncthreads();
    {
      float oacc[4][4];
#pragma unroll
      for (int s2 = 0; s2 < 4; ++s2)
#pragma unroll
        for (int u = 0; u < 4; ++u) oacc[s2][u] = 0.0f;
#pragma unroll 4
      for (int j = 0; j < H_; j += 2) {
        float2 av[4], vv[4];
#pragma unroll
        for (int u = 0; u < 4; ++u) av[u] = *(const float2*)&sm.att[ai0 + u][j];
#pragma unroll
        for (int s2 = 0; s2 < 4; ++s2) vv[s2] = *(const float2*)&sm.s.vchunk[acc0 + s2][j];
#pragma unroll
        for (int s2 = 0; s2 < 4; ++s2)
#pragma unroll
          for (int u = 0; u < 4; ++u)
            oacc[s2][u] += vv[s2].x * av[u].x + vv[s2].y * av[u].y;
      }
#pragma unroll
      for (int s2 = 0; s2 < 4; ++s2) {
        const int cg = ch * 32 + acc0 + s2;
        float4 st;
        st.x = oacc[s2][0]; st.y = oacc[s2][1]; st.z = oacc[s2][2]; st.w = oacc[s2][3];
        *(float4*)&o_t[(((size_t)b * CH_ + cg) * W_ + w) * H_ + ai0] = st;
      }
    }
    __syncthreads();
  }
}

__global__ __launch_bounds__(256)
void k2_epi(const float* __restrict__ o_t, const float* __restrict__ x,
            const float* __restrict__ gamma, float* __restrict__ out) {
  const int pr = blockIdx.x % 10;
  const int plane = blockIdx.x / 10;
  const int rT[10] = {0, 0, 0, 0, 1, 1, 1, 2, 2, 3};
  const int sT[10] = {0, 1, 2, 3, 1, 2, 3, 2, 3, 3};
  const int r = rT[pr], s = sT[pr];
  __shared__ float t1[32][33];
  __shared__ float t2[32][33];
  const int t = threadIdx.x;
  const size_t pbase = (size_t)plane * (H_ * W_);
  const float* ob = o_t + pbase;
#pragma unroll
  for (int ii = 0; ii < 4; ++ii) {
    const int idx = ii * 256 + t;
    const int ww = idx >> 5, hh = idx & 31;
    t1[ww][hh] = ob[(s * 32 + ww) * H_ + (r * 32 + hh)];
    if (r != s) t2[ww][hh] = ob[(r * 32 + ww) * H_ + (s * 32 + hh)];
  }
  __syncthreads();
  const float g = gamma[0];
#pragma unroll
  for (int ii = 0; ii < 4; ++ii) {
    const int idx = ii * 256 + t;
    const int hh = idx >> 5, ww = idx & 31;
    const size_t o1 = pbase + (size_t)(r * 32 + hh) * W_ + (s * 32 + ww);
    out[o1] = g * t1[ww][hh] + x[o1];
    if (r != s) {
      const size_t o2 = pbase + (size_t)(s * 32 + hh) * W_ + (r * 32 + ww);
      out[o2] = g * t2[ww][hh] + x[o2];
    }
  }
}

// ---------------- launch ----------------

extern "C" void kernel_launch(void* const* d_in, const int* in_sizes, int n_in,
                              void* d_out, int out_size, void* d_ws, size_t ws_size,
                              hipStream_t stream) {
  const float* x     = (const float*)d_in[0];
  const float* Wq    = (const float*)d_in[1];
  const float* bq    = (const float*)d_in[2];
  const float* Wk    = (const float*)d_in[3];
  const float* bk    = (const float*)d_in[4];
  const float* Wv    = (const float*)d_in[5];
  const float* bv    = (const float*)d_in[6];
  const float* gamma = (const float*)d_in[7];
  float* out = (float*)d_out;

  const size_t XT   = (size_t)B_ * W_ * H_ * CH_ * 2;  // 64 MiB bf16
  const size_t YT   = XT;                              // 64 MiB bf16
  const size_t WQKB = 64 * 256 * 2;
  const size_t WVB  = 256 * 256 * 2;
  const size_t FAST_WS = XT + YT + WQKB + WVB;

  if (ws_size >= FAST_WS) {
    unsigned short* xt  = (unsigned short*)d_ws;
    unsigned short* yb  = (unsigned short*)((char*)d_ws + XT);
    unsigned short* wqk = (unsigned short*)((char*)d_ws + XT + YT);
    unsigned short* wvb = (unsigned short*)((char*)d_ws + XT + YT + WQKB);
    hipLaunchKernelGGL(kw_pack, dim3(320), dim3(256), 0, stream, Wq, Wk, Wv, wqk, wvb);
    hipLaunchKernelGGL(k0_xpose, dim3(B_ * H_), dim3(256), 0, stream, x, xt);
    hipLaunchKernelGGL(k1y, dim3(B_ * W_), dim3(256), 0, stream,
                       xt, wqk, bq, bk, yb);
    hipLaunchKernelGGL(k2g, dim3(B_ * H_ * 2), dim3(256), 0, stream,
                       yb, wvb, bv, gamma, x, out);
  } else {
    const size_t OT_F = (size_t)B_ * CH_ * H_ * W_ * sizeof(float);
    float* o_t = (ws_size >= OT_F) ? (float*)d_ws : out;
    hipLaunchKernelGGL(k1_attn, dim3(B_ * W_), dim3(256), 0, stream,
                       x, Wq, bq, Wk, bk, Wv, bv, o_t);
    hipLaunchKernelGGL(k2_epi, dim3((B_ * CH_) * 10), dim3(256), 0, stream,
                       o_t, x, gamma, out);
  }
}